// Round 11
// baseline (180.154 us; speedup 1.0000x reference)
//
#include <hip/hip_runtime.h>
#include <hip/hip_bf16.h>
#include <math.h>

#define DIMSZ 1024
#define NHEAD 16
#define HDIM 64
#define BATCH 2
#define SEQ 2048
#define NROWS (BATCH * SEQ)   // 4096

// softmax in exp2 domain: fold 1/sqrt(64) * log2(e) into Q at conversion
#define QSCALE 0.18033688011112042592f

typedef __attribute__((ext_vector_type(8))) _Float16 f16x8;
typedef __attribute__((ext_vector_type(2))) __fp16 fp16x2;   // cvt_pkrtz return type
typedef __attribute__((ext_vector_type(4))) float f32x4;

// float -> fp16 RNE, as bit pattern
__device__ __forceinline__ ushort f2h(float x) {
    union { _Float16 h; ushort u; } cv;
    cv.h = (_Float16)x;
    return cv.u;
}

// packed f32x2 -> f16x2 (RTZ), one v_cvt_pkrtz_f16_f32
__device__ __forceinline__ unsigned pkrtz(float a, float b) {
    union { fp16x2 v; unsigned u; } c;
    c.v = __builtin_amdgcn_cvt_pkrtz(a, b);
    return c.u;
}

__device__ __forceinline__ void gld16(const void* g, void* l) {
    __builtin_amdgcn_global_load_lds((const __attribute__((address_space(1))) void*)g,
                                     (__attribute__((address_space(3))) void*)l,
                                     16, 0, 0);
}

// ---------------------------------------------------------------------------
// Convert everything to fp16 single-plane. (unchanged)
// ---------------------------------------------------------------------------
__global__ __launch_bounds__(256) void convert_all(
    const float* __restrict__ x,
    const float* __restrict__ Wq, const float* __restrict__ Wk,
    const float* __restrict__ Wv, const float* __restrict__ Wo,
    ushort* __restrict__ Xh, ushort* __restrict__ Wh, ushort* __restrict__ Woh)
{
    const int b = blockIdx.x;
    const float* src;
    ushort* dst;
    size_t off;
    if (b < 2048)      { src = x;  dst = Xh;             off = (size_t)b * 2048; }
    else if (b < 2560) { src = Wq; dst = Wh;             off = (size_t)(b - 2048) * 2048; }
    else if (b < 3072) { src = Wk; dst = Wh + (1 << 20); off = (size_t)(b - 2560) * 2048; }
    else if (b < 3584) { src = Wv; dst = Wh + 2 * (1 << 20); off = (size_t)(b - 3072) * 2048; }
    else               { src = Wo; dst = Woh;            off = (size_t)(b - 3584) * 2048; }

    const size_t i = off + (size_t)threadIdx.x * 8;
    const float4 f0 = *(const float4*)&src[i];
    const float4 f1 = *(const float4*)&src[i + 4];
    uint4 hv;
    hv.x = (unsigned)f2h(f0.x) | ((unsigned)f2h(f0.y) << 16);
    hv.y = (unsigned)f2h(f0.z) | ((unsigned)f2h(f0.w) << 16);
    hv.z = (unsigned)f2h(f1.x) | ((unsigned)f2h(f1.y) << 16);
    hv.w = (unsigned)f2h(f1.z) | ((unsigned)f2h(f1.w) << 16);
    *(uint4*)&dst[i] = hv;
}

// ---------------------------------------------------------------------------
// Fused QKV GEMM, fp16.
// r11: flash-proven loop skeleton — double-buffered LDS, ONE barrier per
//      K-step (was 2): barrier -> issue next-tile gld16 -> ds_read cur ->
//      MFMA. The pre-barrier vmcnt drain now overlaps a full compute window.
//      + K-phase stagger (kk0 = (bx&1)*8; K-accumulation commutative) so
//      co-resident blocks desync barrier phases. XOR-8 zero-conflict layout
//      kept (r10). LDS: 2 x 32KB dbuf; epilogue reuses 34KB. 2 blocks/CU.
// ---------------------------------------------------------------------------
__global__ __launch_bounds__(256) void qkv_gemm(
    const ushort* __restrict__ Xh,
    const ushort* __restrict__ Wh,
    const float* __restrict__ bq, const float* __restrict__ bk,
    const float* __restrict__ bv,
    ushort* __restrict__ Qb, ushort* __restrict__ Kb, ushort* __restrict__ Vt)
{
    __shared__ __align__(16) ushort smem[32768];   // 64KB: buf b at b*16384

    const int tid = threadIdx.x;
    const int wave = tid >> 6;
    const int lane = tid & 63;
    const int lm = lane & 15;
    const int lq = lane >> 4;
    const int wy = wave >> 1;
    const int wx = wave & 1;
    const int m0 = blockIdx.x * 128;
    const int nbase = blockIdx.y * 128;

    // staging: thread t -> row r0 = t>>3 (+32/+64/+96), slot c = t&7,
    // global chunk g = c ^ (r0&7). LDS dest linear: tid*8 ushorts.
    const int c = tid & 7;
    const int r0 = tid >> 3;               // 0..31
    const int g = c ^ (r0 & 7);
    const ushort* gah = Xh + (size_t)(m0 + r0) * DIMSZ + g * 8;
    const ushort* gbh = Wh + (size_t)(nbase + r0) * DIMSZ + g * 8;
    const int tofs = tid * 8;

    // K-phase stagger between (likely) co-resident neighbor blocks
    const int kk0 = (blockIdx.x & 1) * 8;

    // frag read offsets within a buffer: [128][64] row-major; slot s of row r
    // holds global chunk s^(r&7); row = (wy|wx)*64 + i*16 + lm (row&7==lm&7)
    int aofs[4][2], bofs[4][2];
#pragma unroll
    for (int i = 0; i < 4; ++i)
#pragma unroll
        for (int kt = 0; kt < 2; ++kt) {
            const int slot = ((kt * 4 + lq) ^ (lm & 7)) << 3;
            aofs[i][kt] = (wy * 64 + i * 16 + lm) * 64 + slot;
            bofs[i][kt] = 8192 + (wx * 64 + i * 16 + lm) * 64 + slot;
        }

    f32x4 acc[4][4] = {};

    // prologue: stage K-tile kk0 into buf 0
    {
        const int k0 = kk0 * 64;
#pragma unroll
        for (int gg = 0; gg < 4; ++gg) {
            gld16(gah + gg * 32 * DIMSZ + k0, smem + gg * 2048 + tofs);
            gld16(gbh + gg * 32 * DIMSZ + k0, smem + 8192 + gg * 2048 + tofs);
        }
    }

    for (int it = 0; it < 16; ++it) {
        __syncthreads();   // tile it staged (vmcnt drain) + prior reads done

        if (it + 1 < 16) {
            const int k0 = ((kk0 + it + 1) & 15) * 64;
            ushort* nb = smem + ((it + 1) & 1) * 16384;
#pragma unroll
            for (int gg = 0; gg < 4; ++gg) {
                gld16(gah + gg * 32 * DIMSZ + k0, nb + gg * 2048 + tofs);
                gld16(gbh + gg * 32 * DIMSZ + k0, nb + 8192 + gg * 2048 + tofs);
            }
        }

        const ushort* cb = smem + (it & 1) * 16384;

        f16x8 a0[4], b0[4];
#pragma unroll
        for (int i = 0; i < 4; ++i) {
            a0[i] = *(const f16x8*)&cb[aofs[i][0]];
            b0[i] = *(const f16x8*)&cb[bofs[i][0]];
        }
#pragma unroll
        for (int i = 0; i < 4; ++i)
#pragma unroll
            for (int j = 0; j < 4; ++j)
                acc[i][j] = __builtin_amdgcn_mfma_f32_16x16x32_f16(a0[i], b0[j], acc[i][j], 0, 0, 0);

        f16x8 a1[4], b1[4];
#pragma unroll
        for (int i = 0; i < 4; ++i) {
            a1[i] = *(const f16x8*)&cb[aofs[i][1]];
            b1[i] = *(const f16x8*)&cb[bofs[i][1]];
        }
#pragma unroll
        for (int i = 0; i < 4; ++i)
#pragma unroll
            for (int j = 0; j < 4; ++j)
                acc[i][j] = __builtin_amdgcn_mfma_f32_16x16x32_f16(a1[i], b1[j], acc[i][j], 0, 0, 0);
    }

    const int mat = blockIdx.y >> 3;      // 0:Q 1:K 2:V (block-uniform)
    const float* bias = (mat == 0) ? bq : (mat == 1) ? bk : bv;
    const int nloc0 = (blockIdx.y & 7) * 128;
    const int b = m0 >> 11;
    const int s0 = m0 & (SEQ - 1);
    ushort* sf = smem;

    __syncthreads();   // K-loop traffic complete before smem reuse

    if (mat == 2) {
        // ---- V: transpose to [d][s], key-permuted within 32-blocks
#pragma unroll
        for (int j = 0; j < 4; ++j) {
            const int nc = nloc0 + wx * 64 + j * 16 + lm;
            const float bb = bias[nc];
            const int d = j * 16 + lm;
#pragma unroll
            for (int i = 0; i < 4; ++i) {
                const int ss = wy * 64 + (i >> 1) * 32 + lq * 8 + (i & 1) * 4;
                ushort4 pk;
                pk.x = f2h(acc[i][j][0] + bb);
                pk.y = f2h(acc[i][j][1] + bb);
                pk.z = f2h(acc[i][j][2] + bb);
                pk.w = f2h(acc[i][j][3] + bb);
                *(ushort4*)&sf[(wx * 64 + d) * 136 + ss] = pk;
            }
        }
        __syncthreads();
#pragma unroll
        for (int p = 0; p < 8; ++p) {
            const int idx = p * 256 + tid;
            const int row = idx >> 4;
            const int hh = row >> 6;
            const int d = row & 63;
            const int sseg = (idx & 15) * 8;
            const uint4 v = *(const uint4*)&sf[row * 136 + sseg];
            const int hg = (nloc0 >> 6) + hh;
            *(uint4*)&Vt[((size_t)(b * NHEAD + hg) * HDIM + d) * SEQ + s0 + sseg] = v;
        }
    } else {
        // ---- Q/K: [s][d] tile in LDS, uint4 coalesced out
        ushort* dst = (mat == 0) ? Qb : Kb;
        const float sc = (mat == 0) ? QSCALE : 1.0f;
#pragma unroll
        for (int j = 0; j < 4; ++j) {
            const int col = wx * 64 + j * 16 + lm;
            const float bb = bias[nloc0 + col];
#pragma unroll
            for (int i = 0; i < 4; ++i) {
                const int rbase = wy * 64 + i * 16 + lq * 4;
#pragma unroll
                for (int rr = 0; rr < 4; ++rr)
                    sf[(rbase + rr) * 136 + col] = f2h((acc[i][j][rr] + bb) * sc);
            }
        }
        __syncthreads();
#pragma unroll
        for (int p = 0; p < 8; ++p) {
            const int idx = p * 256 + tid;
            const int row = idx >> 4;
            const int seg = idx & 15;
            const uint4 v = *(const uint4*)&sf[row * 136 + seg * 8];
            const int nc0 = nloc0 + seg * 8;
            const int h = nc0 >> 6;
            const int d = nc0 & 63;
            *(uint4*)&dst[((size_t)(b * NHEAD + h) * SEQ + s0 + row) * HDIM + d] = v;
        }
    }
}

// ---------------------------------------------------------------------------
// MFMA flash attention, S^T formulation, fp16. (unchanged from r9/r10)
// ---------------------------------------------------------------------------
__global__ __launch_bounds__(256, 2) void flash_attn_mfma(
    const ushort* __restrict__ Qb, const ushort* __restrict__ Kb,
    const ushort* __restrict__ Vt, ushort* __restrict__ CTXh)
{
    __shared__ __align__(16) ushort Ks[2][8192];   // 128 s-rows x 64 k (16KB each)
    __shared__ __align__(16) ushort Vs[2][8192];   // 2 halves x [64 d x 64 s] (16KB each)

    const int tid = threadIdx.x;
    const int w = tid >> 6;        // 0..3
    const int l = tid & 63;
    const int lm = l & 15;
    const int lq = l >> 4;
    const int q0 = blockIdx.x * 128;
    const int bh = blockIdx.y;
    const int NCH = SEQ / 128;     // 16

    const int ch0 = (bh >> 4) * 8;

    const ushort* Kg = Kb + (size_t)bh * SEQ * HDIM;
    const ushort* Vg = Vt + (size_t)bh * HDIM * SEQ;

    const int sr8 = l >> 3;                          // 0..7
    const int sg_ = (l & 7) ^ (sr8 & 7);

    f16x8 qf[2][2];
#pragma unroll
    for (int rt = 0; rt < 2; ++rt)
#pragma unroll
        for (int kt = 0; kt < 2; ++kt)
            qf[rt][kt] = *(const f16x8*)&Qb[((size_t)bh * SEQ + q0 + w * 32 + rt * 16 + lm) * HDIM + kt * 32 + lq * 8];

    int kbase[2], vbase[4];
#pragma unroll
    for (int kt = 0; kt < 2; ++kt)
        kbase[kt] = lm * 64 + (((kt * 4 + lq) ^ (lm & 7)) << 3);
#pragma unroll
    for (int kt2 = 0; kt2 < 4; ++kt2)
        vbase[kt2] = (kt2 >> 1) * 4096 + lm * 64 + ((((kt2 & 1) * 4 + lq) ^ (lm & 7)) << 3);

    f16x8 vones;
#pragma unroll
    for (int i = 0; i < 8; ++i) vones[i] = (_Float16)1.0f;

    f32x4 o[2][4] = {};
    f32x4 lacc[2] = {};

    {
        const int kc0 = ch0 * 128;
#pragma unroll
        for (int p = 0; p < 2; ++p) {
            const int kr = kc0 + p * 64 + w * 16 + sr8;
            gld16(Kg + (size_t)kr * HDIM + sg_ * 8,        &Ks[0][0] + p * 4096 + w * 1024);
            gld16(Kg + (size_t)(kr + 8) * HDIM + sg_ * 8,  &Ks[0][0] + p * 4096 + w * 1024 + 512);
            const int vr = w * 16 + sr8;
            gld16(Vg + (size_t)vr * SEQ + kc0 + p * 64 + sg_ * 8,       &Vs[0][0] + p * 4096 + w * 1024);
            gld16(Vg + (size_t)(vr + 8) * SEQ + kc0 + p * 64 + sg_ * 8, &Vs[0][0] + p * 4096 + w * 1024 + 512);
        }
    }

    for (int it = 0; it < NCH; ++it) {
        __syncthreads();

        if (it + 1 < NCH) {
            const int kc = ((ch0 + it + 1) & (NCH - 1)) * 128;
            ushort* kb_n = &Ks[(it + 1) & 1][0];
            ushort* vb_n = &Vs[(it + 1) & 1][0];
#pragma unroll
            for (int p = 0; p < 2; ++p) {
                const int kr = kc + p * 64 + w * 16 + sr8;
                gld16(Kg + (size_t)kr * HDIM + sg_ * 8,        kb_n + p * 4096 + w * 1024);
                gld16(Kg + (size_t)(kr + 8) * HDIM + sg_ * 8,  kb_n + p * 4096 + w * 1024 + 512);
                const int vr = w * 16 + sr8;
                gld16(Vg + (size_t)vr * SEQ + kc + p * 64 + sg_ * 8,       vb_n + p * 4096 + w * 1024);
                gld16(Vg + (size_t)(vr + 8) * SEQ + kc + p * 64 + sg_ * 8, vb_n + p * 4096 + w * 1024 + 512);
            }
        }

        const ushort* kb = &Ks[it & 1][0];
        const ushort* vb = &Vs[it & 1][0];

        f32x4 st[2][8] = {};
        __builtin_amdgcn_s_setprio(1);
#pragma unroll
        for (int ct = 0; ct < 8; ++ct)
#pragma unroll
            for (int kt = 0; kt < 2; ++kt) {
                const f16x8 kf = *(const f16x8*)&kb[ct * 1024 + kbase[kt]];
                st[0][ct] = __builtin_amdgcn_mfma_f32_16x16x32_f16(kf, qf[0][kt], st[0][ct], 0, 0, 0);
                st[1][ct] = __builtin_amdgcn_mfma_f32_16x16x32_f16(kf, qf[1][kt], st[1][ct], 0, 0, 0);
            }
        __builtin_amdgcn_s_setprio(0);

#pragma unroll
        for (int rt = 0; rt < 2; ++rt)
#pragma unroll
            for (int ct = 0; ct < 8; ++ct)
#pragma unroll
                for (int r = 0; r < 4; ++r)
                    st[rt][ct][r] = __builtin_amdgcn_exp2f(st[rt][ct][r]);

        f16x8 pf[2][4];
#pragma unroll
        for (int rt = 0; rt < 2; ++rt)
#pragma unroll
            for (int kt2 = 0; kt2 < 4; ++kt2) {
                union { f16x8 v; unsigned u[4]; } pk;
#pragma unroll
                for (int t = 0; t < 2; ++t) {
                    pk.u[t * 2 + 0] = pkrtz(st[rt][kt2 * 2 + t][0], st[rt][kt2 * 2 + t][1]);
                    pk.u[t * 2 + 1] = pkrtz(st[rt][kt2 * 2 + t][2], st[rt][kt2 * 2 + t][3]);
                }
                pf[rt][kt2] = pk.v;
            }

        __builtin_amdgcn_s_setprio(1);
#pragma unroll
        for (int kt2 = 0; kt2 < 4; ++kt2) {
            lacc[0] = __builtin_amdgcn_mfma_f32_16x16x32_f16(pf[0][kt2], vones, lacc[0], 0, 0, 0);
            lacc[1] = __builtin_amdgcn_mfma_f32_16x16x32_f16(pf[1][kt2], vones, lacc[1], 0, 0, 0);
        }

#pragma unroll
        for (int dt = 0; dt < 4; ++dt)
#pragma unroll
            for (int kt2 = 0; kt2 < 4; ++kt2) {
                const f16x8 vf = *(const f16x8*)&vb[dt * 1024 + vbase[kt2]];
                o[0][dt] = __builtin_amdgcn_mfma_f32_16x16x32_f16(pf[0][kt2], vf, o[0][dt], 0, 0, 0);
                o[1][dt] = __builtin_amdgcn_mfma_f32_16x16x32_f16(pf[1][kt2], vf, o[1][dt], 0, 0, 0);
            }
        __builtin_amdgcn_s_setprio(0);
    }

    const int b = bh >> 4;
    const int h = bh & 15;
#pragma unroll
    for (int rt = 0; rt < 2; ++rt)
#pragma unroll
    for (int r = 0; r < 4; ++r) {
        const float lr = 1.0f / lacc[rt][r];
        const int srow2 = q0 + w * 32 + rt * 16 + lq * 4 + r;
        const size_t base = ((size_t)b * SEQ + srow2) * DIMSZ + h * HDIM;
#pragma unroll
        for (int dt = 0; dt < 4; ++dt)
            CTXh[base + dt * 16 + lm] = f2h(o[rt][dt][r] * lr);
    }
}

// ---------------------------------------------------------------------------
// Output projection: fp16 (CTXh x Woh).
// r11: single-barrier dbuf loop (flash skeleton) + K-phase stagger.
// 64x128 tiles, 512 blocks (2/CU), LDS 48KB: buf b at b*12288,
// A [64][64] at 0..4095, B [128][64] at 4096..12287.
// ---------------------------------------------------------------------------
__global__ __launch_bounds__(256) void oproj_gemm(
    const ushort* __restrict__ Ah_g, const ushort* __restrict__ Bh_g,
    const float* __restrict__ bias, float* __restrict__ out)
{
    __shared__ __align__(16) ushort smem[24576];

    const int tid = threadIdx.x;
    const int wave = tid >> 6;
    const int lane = tid & 63;
    const int lm = lane & 15;
    const int lq = lane >> 4;
    const int wy = wave >> 1;
    const int wx = wave & 1;
    const int m0 = blockIdx.x * 64;
    const int n0 = blockIdx.y * 128;

    const int c = tid & 7;
    const int r0 = tid >> 3;               // 0..31
    const int g = c ^ (r0 & 7);
    const ushort* gah = Ah_g + (size_t)(m0 + r0) * DIMSZ + g * 8;
    const ushort* gbh = Bh_g + (size_t)(n0 + r0) * DIMSZ + g * 8;
    const int tofs = tid * 8;

    const int kk0 = (blockIdx.x & 1) * 8;

    int aofs[2][2], bofs[4][2];
#pragma unroll
    for (int kt = 0; kt < 2; ++kt) {
        const int slot = ((kt * 4 + lq) ^ (lm & 7)) << 3;
#pragma unroll
        for (int i = 0; i < 2; ++i)
            aofs[i][kt] = (wy * 32 + i * 16 + lm) * 64 + slot;
#pragma unroll
        for (int j = 0; j < 4; ++j)
            bofs[j][kt] = 4096 + (wx * 64 + j * 16 + lm) * 64 + slot;
    }

    f32x4 acc[2][4] = {};

    // prologue: stage K-tile kk0 into buf 0
    {
        const int k0 = kk0 * 64;
        gld16(gah + k0, smem + tofs);
        gld16(gah + 32 * DIMSZ + k0, smem + 2048 + tofs);
#pragma unroll
        for (int gg = 0; gg < 4; ++gg)
            gld16(gbh + gg * 32 * DIMSZ + k0, smem + 4096 + gg * 2048 + tofs);
    }

    for (int it = 0; it < 16; ++it) {
        __syncthreads();   // tile it staged + prior reads done

        if (it + 1 < 16) {
            const int k0 = ((kk0 + it + 1) & 15) * 64;
            ushort* nb = smem + ((it + 1) & 1) * 12288;
            gld16(gah + k0, nb + tofs);
            gld16(gah + 32 * DIMSZ + k0, nb + 2048 + tofs);
#pragma unroll
            for (int gg = 0; gg < 4; ++gg)
                gld16(gbh + gg * 32 * DIMSZ + k0, nb + 4096 + gg * 2048 + tofs);
        }

        const ushort* cb = smem + (it & 1) * 12288;

        f16x8 a0[2], b0[4];
#pragma unroll
        for (int i = 0; i < 2; ++i) a0[i] = *(const f16x8*)&cb[aofs[i][0]];
#pragma unroll
        for (int j = 0; j < 4; ++j) b0[j] = *(const f16x8*)&cb[bofs[j][0]];
#pragma unroll
        for (int i = 0; i < 2; ++i)
#pragma unroll
            for (int j = 0; j < 4; ++j)
                acc[i][j] = __builtin_amdgcn_mfma_f32_16x16x32_f16(a0[i], b0[j], acc[i][j], 0, 0, 0);

        f16x8 a1[2], b1[4];
#pragma unroll
        for (int i = 0; i < 2; ++i) a1[i] = *(const f16x8*)&cb[aofs[i][1]];
#pragma unroll
        for (int j = 0; j < 4; ++j) b1[j] = *(const f16x8*)&cb[bofs[j][1]];
#pragma unroll
        for (int i = 0; i < 2; ++i)
#pragma unroll
            for (int j = 0; j < 4; ++j)
                acc[i][j] = __builtin_amdgcn_mfma_f32_16x16x32_f16(a1[i], b1[j], acc[i][j], 0, 0, 0);
    }

#pragma unroll
    for (int j = 0; j < 4; ++j) {
        const int nc = n0 + wx * 64 + j * 16 + lm;
        const float bb = bias[nc];
#pragma unroll
        for (int i = 0; i < 2; ++i) {
            const int mb = m0 + wy * 32 + i * 16 + lq * 4;
#pragma unroll
            for (int rr = 0; rr < 4; ++rr)
                out[(size_t)(mb + rr) * DIMSZ + nc] = acc[i][j][rr] + bb;
        }
    }
}

// ---------------------------------------------------------------------------
extern "C" void kernel_launch(void* const* d_in, const int* in_sizes, int n_in,
                              void* d_out, int out_size, void* d_ws, size_t ws_size,
                              hipStream_t stream)
{
    const float* x  = (const float*)d_in[0];
    const float* Wq = (const float*)d_in[1];
    const float* bq = (const float*)d_in[2];
    const float* Wk = (const float*)d_in[3];
    const float* bk = (const float*)d_in[4];
    const float* Wv = (const float*)d_in[5];
    const float* bv = (const float*)d_in[6];
    const float* Wo = (const float*)d_in[7];
    const float* bo = (const float*)d_in[8];
    float* out = (float*)d_out;

    const size_t elems = (size_t)NROWS * DIMSZ;   // 4M
    ushort* Qb   = (ushort*)d_ws;                 // 8MB
    ushort* Kb   = Qb + elems;                    // 8MB
    ushort* Vt   = Kb + elems;                    // 8MB
    ushort* CTXh = Vt + elems;                    // 8MB (overlay: Xh)
    ushort* Wh   = CTXh + elems;                  // 6MB
    ushort* Woh  = Wh + 3 * (1 << 20);            // 2MB  (peak 40MB)
    ushort* Xh   = CTXh;                          // dead before flash writes CTX

    convert_all<<<4096, 256, 0, stream>>>(x, Wq, Wk, Wv, Wo, Xh, Wh, Woh);

    qkv_gemm<<<dim3(32, 24), 256, 0, stream>>>(Xh, Wh, bq, bk, bv, Qb, Kb, Vt);

    flash_attn_mfma<<<dim3(SEQ / 128, BATCH * NHEAD), 256, 0, stream>>>(Qb, Kb, Vt, CTXh);

    oproj_gemm<<<dim3(64, 8), 256, 0, stream>>>(CTXh, Woh, bo, out);
}

// Round 12
// 171.124 us; speedup vs baseline: 1.0528x; 1.0528x over previous
//
#include <hip/hip_runtime.h>
#include <hip/hip_bf16.h>
#include <math.h>

#define DIMSZ 1024
#define NHEAD 16
#define HDIM 64
#define BATCH 2
#define SEQ 2048
#define NROWS (BATCH * SEQ)   // 4096

// softmax in exp2 domain: fold 1/sqrt(64) * log2(e) into Q at conversion
#define QSCALE 0.18033688011112042592f

typedef __attribute__((ext_vector_type(8))) _Float16 f16x8;
typedef __attribute__((ext_vector_type(2))) __fp16 fp16x2;   // cvt_pkrtz return type
typedef __attribute__((ext_vector_type(4))) float f32x4;

// float -> fp16 RNE, as bit pattern
__device__ __forceinline__ ushort f2h(float x) {
    union { _Float16 h; ushort u; } cv;
    cv.h = (_Float16)x;
    return cv.u;
}

// packed f32x2 -> f16x2 (RTZ), one v_cvt_pkrtz_f16_f32
__device__ __forceinline__ unsigned pkrtz(float a, float b) {
    union { fp16x2 v; unsigned u; } c;
    c.v = __builtin_amdgcn_cvt_pkrtz(a, b);
    return c.u;
}

__device__ __forceinline__ void gld16(const void* g, void* l) {
    __builtin_amdgcn_global_load_lds((const __attribute__((address_space(1))) void*)g,
                                     (__attribute__((address_space(3))) void*)l,
                                     16, 0, 0);
}

// ---------------------------------------------------------------------------
// Convert everything to fp16 single-plane. (unchanged)
// ---------------------------------------------------------------------------
__global__ __launch_bounds__(256) void convert_all(
    const float* __restrict__ x,
    const float* __restrict__ Wq, const float* __restrict__ Wk,
    const float* __restrict__ Wv, const float* __restrict__ Wo,
    ushort* __restrict__ Xh, ushort* __restrict__ Wh, ushort* __restrict__ Woh)
{
    const int b = blockIdx.x;
    const float* src;
    ushort* dst;
    size_t off;
    if (b < 2048)      { src = x;  dst = Xh;             off = (size_t)b * 2048; }
    else if (b < 2560) { src = Wq; dst = Wh;             off = (size_t)(b - 2048) * 2048; }
    else if (b < 3072) { src = Wk; dst = Wh + (1 << 20); off = (size_t)(b - 2560) * 2048; }
    else if (b < 3584) { src = Wv; dst = Wh + 2 * (1 << 20); off = (size_t)(b - 3072) * 2048; }
    else               { src = Wo; dst = Woh;            off = (size_t)(b - 3584) * 2048; }

    const size_t i = off + (size_t)threadIdx.x * 8;
    const float4 f0 = *(const float4*)&src[i];
    const float4 f1 = *(const float4*)&src[i + 4];
    uint4 hv;
    hv.x = (unsigned)f2h(f0.x) | ((unsigned)f2h(f0.y) << 16);
    hv.y = (unsigned)f2h(f0.z) | ((unsigned)f2h(f0.w) << 16);
    hv.z = (unsigned)f2h(f1.x) | ((unsigned)f2h(f1.y) << 16);
    hv.w = (unsigned)f2h(f1.z) | ((unsigned)f2h(f1.w) << 16);
    *(uint4*)&dst[i] = hv;
}

// ---------------------------------------------------------------------------
// Fused QKV GEMM, fp16. (r10 form restored — two-barrier BK=64 loop, XOR-8
// zero-conflict layout; r11's single-barrier dbuf regressed, reverted.)
// ---------------------------------------------------------------------------
__global__ __launch_bounds__(256, 3) void qkv_gemm(
    const ushort* __restrict__ Xh,
    const ushort* __restrict__ Wh,
    const float* __restrict__ bq, const float* __restrict__ bk,
    const float* __restrict__ bv,
    ushort* __restrict__ Qb, ushort* __restrict__ Kb, ushort* __restrict__ Vt)
{
    __shared__ __align__(16) ushort smem[17408];

    const int tid = threadIdx.x;
    const int wave = tid >> 6;
    const int lane = tid & 63;
    const int lm = lane & 15;
    const int lq = lane >> 4;
    const int wy = wave >> 1;
    const int wx = wave & 1;
    const int m0 = blockIdx.x * 128;
    const int nbase = blockIdx.y * 128;

    const int c = tid & 7;
    const int r0 = tid >> 3;               // 0..31
    const int g = c ^ (r0 & 7);
    const ushort* gah = Xh + (size_t)(m0 + r0) * DIMSZ + g * 8;
    const ushort* gbh = Wh + (size_t)(nbase + r0) * DIMSZ + g * 8;
    const int tofs = tid * 8;

    int aofs[4][2], bofs[4][2];
#pragma unroll
    for (int i = 0; i < 4; ++i)
#pragma unroll
        for (int kt = 0; kt < 2; ++kt) {
            const int slot = ((kt * 4 + lq) ^ (lm & 7)) << 3;
            aofs[i][kt] = (wy * 64 + i * 16 + lm) * 64 + slot;
            bofs[i][kt] = 8192 + (wx * 64 + i * 16 + lm) * 64 + slot;
        }

    f32x4 acc[4][4] = {};

    // stage k-tile 0 (8 gld16: 4 A row-groups + 4 B row-groups)
#pragma unroll
    for (int gg = 0; gg < 4; ++gg) {
        gld16(gah + gg * 32 * DIMSZ, smem + gg * 2048 + tofs);
        gld16(gbh + gg * 32 * DIMSZ, smem + 8192 + gg * 2048 + tofs);
    }

    for (int kk = 0; kk < 16; ++kk) {
        __syncthreads();   // barrier1: staging for tile kk landed (vmcnt drain)

        f16x8 a0[4], b0[4];
#pragma unroll
        for (int i = 0; i < 4; ++i) {
            a0[i] = *(const f16x8*)&smem[aofs[i][0]];
            b0[i] = *(const f16x8*)&smem[bofs[i][0]];
        }
#pragma unroll
        for (int i = 0; i < 4; ++i)
#pragma unroll
            for (int j = 0; j < 4; ++j)
                acc[i][j] = __builtin_amdgcn_mfma_f32_16x16x32_f16(a0[i], b0[j], acc[i][j], 0, 0, 0);

        f16x8 a1[4], b1[4];
#pragma unroll
        for (int i = 0; i < 4; ++i) {
            a1[i] = *(const f16x8*)&smem[aofs[i][1]];
            b1[i] = *(const f16x8*)&smem[bofs[i][1]];
        }

        __syncthreads();   // barrier2: all frag reads drained before overwrite

        if (kk + 1 < 16) {
            const int k0 = (kk + 1) * 64;
#pragma unroll
            for (int gg = 0; gg < 4; ++gg) {
                gld16(gah + gg * 32 * DIMSZ + k0, smem + gg * 2048 + tofs);
                gld16(gbh + gg * 32 * DIMSZ + k0, smem + 8192 + gg * 2048 + tofs);
            }
        }

#pragma unroll
        for (int i = 0; i < 4; ++i)
#pragma unroll
            for (int j = 0; j < 4; ++j)
                acc[i][j] = __builtin_amdgcn_mfma_f32_16x16x32_f16(a1[i], b1[j], acc[i][j], 0, 0, 0);
    }

    const int mat = blockIdx.y >> 3;      // 0:Q 1:K 2:V (block-uniform)
    const float* bias = (mat == 0) ? bq : (mat == 1) ? bk : bv;
    const int nloc0 = (blockIdx.y & 7) * 128;
    const int b = m0 >> 11;
    const int s0 = m0 & (SEQ - 1);
    ushort* sf = smem;

    __syncthreads();   // K-loop traffic complete before smem reuse

    if (mat == 2) {
        // ---- V: transpose to [d][s], key-permuted within 32-blocks
#pragma unroll
        for (int j = 0; j < 4; ++j) {
            const int nc = nloc0 + wx * 64 + j * 16 + lm;
            const float bb = bias[nc];
            const int d = j * 16 + lm;
#pragma unroll
            for (int i = 0; i < 4; ++i) {
                const int ss = wy * 64 + (i >> 1) * 32 + lq * 8 + (i & 1) * 4;
                ushort4 pk;
                pk.x = f2h(acc[i][j][0] + bb);
                pk.y = f2h(acc[i][j][1] + bb);
                pk.z = f2h(acc[i][j][2] + bb);
                pk.w = f2h(acc[i][j][3] + bb);
                *(ushort4*)&sf[(wx * 64 + d) * 136 + ss] = pk;
            }
        }
        __syncthreads();
#pragma unroll
        for (int p = 0; p < 8; ++p) {
            const int idx = p * 256 + tid;
            const int row = idx >> 4;
            const int hh = row >> 6;
            const int d = row & 63;
            const int sseg = (idx & 15) * 8;
            const uint4 v = *(const uint4*)&sf[row * 136 + sseg];
            const int hg = (nloc0 >> 6) + hh;
            *(uint4*)&Vt[((size_t)(b * NHEAD + hg) * HDIM + d) * SEQ + s0 + sseg] = v;
        }
    } else {
        // ---- Q/K: [s][d] tile in LDS, uint4 coalesced out
        ushort* dst = (mat == 0) ? Qb : Kb;
        const float sc = (mat == 0) ? QSCALE : 1.0f;
#pragma unroll
        for (int j = 0; j < 4; ++j) {
            const int col = wx * 64 + j * 16 + lm;
            const float bb = bias[nloc0 + col];
#pragma unroll
            for (int i = 0; i < 4; ++i) {
                const int rbase = wy * 64 + i * 16 + lq * 4;
#pragma unroll
                for (int rr = 0; rr < 4; ++rr)
                    sf[(rbase + rr) * 136 + col] = f2h((acc[i][j][rr] + bb) * sc);
            }
        }
        __syncthreads();
#pragma unroll
        for (int p = 0; p < 8; ++p) {
            const int idx = p * 256 + tid;
            const int row = idx >> 4;
            const int seg = idx & 15;
            const uint4 v = *(const uint4*)&sf[row * 136 + seg * 8];
            const int nc0 = nloc0 + seg * 8;
            const int h = nc0 >> 6;
            const int d = nc0 & 63;
            *(uint4*)&dst[((size_t)(b * NHEAD + h) * SEQ + s0 + row) * HDIM + d] = v;
        }
    }
}

// ---------------------------------------------------------------------------
// MFMA flash attention, S^T formulation, fp16.
// r12: INTRA-WAVE ILP — split the 128-chunk into two independent 64-halves
//      and pipeline inside the iteration:
//        QK(h0) -> [QK(h1) || exp2(h0)] -> pack/lacc(h0)
//                -> [PV(h0) || exp2(h1)] -> pack/lacc(h1) -> PV(h1)
//      The bracketed pairs are data-independent MFMA||VALU streams, so the
//      wave dual-issues instead of serializing (r8/r10: MfmaUtil 34 + VALU
//      33, additive). No sync/buffer changes — pure reordering.
//      Geometry from r10: 4 waves x 32 q-rows, KVBLK=128 dbuf, two 64-wide
//      V half-tiles, MFMA row-sum, pkrtz, R9 stagger kept.
// ---------------------------------------------------------------------------
__global__ __launch_bounds__(256, 2) void flash_attn_mfma(
    const ushort* __restrict__ Qb, const ushort* __restrict__ Kb,
    const ushort* __restrict__ Vt, ushort* __restrict__ CTXh)
{
    __shared__ __align__(16) ushort Ks[2][8192];   // 128 s-rows x 64 k (16KB each)
    __shared__ __align__(16) ushort Vs[2][8192];   // 2 halves x [64 d x 64 s] (16KB each)

    const int tid = threadIdx.x;
    const int w = tid >> 6;        // 0..3
    const int l = tid & 63;
    const int lm = l & 15;
    const int lq = l >> 4;
    const int q0 = blockIdx.x * 128;
    const int bh = blockIdx.y;
    const int NCH = SEQ / 128;     // 16

    const int ch0 = (bh >> 4) * 8;

    const ushort* Kg = Kb + (size_t)bh * SEQ * HDIM;
    const ushort* Vg = Vt + (size_t)bh * HDIM * SEQ;

    const int sr8 = l >> 3;                          // 0..7
    const int sg_ = (l & 7) ^ (sr8 & 7);

    f16x8 qf[2][2];
#pragma unroll
    for (int rt = 0; rt < 2; ++rt)
#pragma unroll
        for (int kt = 0; kt < 2; ++kt)
            qf[rt][kt] = *(const f16x8*)&Qb[((size_t)bh * SEQ + q0 + w * 32 + rt * 16 + lm) * HDIM + kt * 32 + lq * 8];

    int kbase[2], vbase[4];
#pragma unroll
    for (int kt = 0; kt < 2; ++kt)
        kbase[kt] = lm * 64 + (((kt * 4 + lq) ^ (lm & 7)) << 3);
#pragma unroll
    for (int kt2 = 0; kt2 < 4; ++kt2)
        vbase[kt2] = (kt2 >> 1) * 4096 + lm * 64 + ((((kt2 & 1) * 4 + lq) ^ (lm & 7)) << 3);

    f16x8 vones;
#pragma unroll
    for (int i = 0; i < 8; ++i) vones[i] = (_Float16)1.0f;

    f32x4 o[2][4] = {};
    f32x4 lacc[2] = {};

    {
        const int kc0 = ch0 * 128;
#pragma unroll
        for (int p = 0; p < 2; ++p) {
            const int kr = kc0 + p * 64 + w * 16 + sr8;
            gld16(Kg + (size_t)kr * HDIM + sg_ * 8,        &Ks[0][0] + p * 4096 + w * 1024);
            gld16(Kg + (size_t)(kr + 8) * HDIM + sg_ * 8,  &Ks[0][0] + p * 4096 + w * 1024 + 512);
            const int vr = w * 16 + sr8;
            gld16(Vg + (size_t)vr * SEQ + kc0 + p * 64 + sg_ * 8,       &Vs[0][0] + p * 4096 + w * 1024);
            gld16(Vg + (size_t)(vr + 8) * SEQ + kc0 + p * 64 + sg_ * 8, &Vs[0][0] + p * 4096 + w * 1024 + 512);
        }
    }

    for (int it = 0; it < NCH; ++it) {
        __syncthreads();

        if (it + 1 < NCH) {
            const int kc = ((ch0 + it + 1) & (NCH - 1)) * 128;
            ushort* kb_n = &Ks[(it + 1) & 1][0];
            ushort* vb_n = &Vs[(it + 1) & 1][0];
#pragma unroll
            for (int p = 0; p < 2; ++p) {
                const int kr = kc + p * 64 + w * 16 + sr8;
                gld16(Kg + (size_t)kr * HDIM + sg_ * 8,        kb_n + p * 4096 + w * 1024);
                gld16(Kg + (size_t)(kr + 8) * HDIM + sg_ * 8,  kb_n + p * 4096 + w * 1024 + 512);
                const int vr = w * 16 + sr8;
                gld16(Vg + (size_t)vr * SEQ + kc + p * 64 + sg_ * 8,       vb_n + p * 4096 + w * 1024);
                gld16(Vg + (size_t)(vr + 8) * SEQ + kc + p * 64 + sg_ * 8, vb_n + p * 4096 + w * 1024 + 512);
            }
        }

        const ushort* kb = &Ks[it & 1][0];
        const ushort* vb = &Vs[it & 1][0];

        f32x4 st[2][8] = {};

        // ---- QK half0 (ct 0..3): pure MFMA
        __builtin_amdgcn_s_setprio(1);
#pragma unroll
        for (int ct = 0; ct < 4; ++ct)
#pragma unroll
            for (int kt = 0; kt < 2; ++kt) {
                const f16x8 kf = *(const f16x8*)&kb[ct * 1024 + kbase[kt]];
                st[0][ct] = __builtin_amdgcn_mfma_f32_16x16x32_f16(kf, qf[0][kt], st[0][ct], 0, 0, 0);
                st[1][ct] = __builtin_amdgcn_mfma_f32_16x16x32_f16(kf, qf[1][kt], st[1][ct], 0, 0, 0);
            }
        __builtin_amdgcn_s_setprio(0);

        // ---- QK half1 (ct 4..7) interleaved with exp2(half0): MFMA || VALU
#pragma unroll
        for (int ct = 4; ct < 8; ++ct) {
#pragma unroll
            for (int kt = 0; kt < 2; ++kt) {
                const f16x8 kf = *(const f16x8*)&kb[ct * 1024 + kbase[kt]];
                st[0][ct] = __builtin_amdgcn_mfma_f32_16x16x32_f16(kf, qf[0][kt], st[0][ct], 0, 0, 0);
                st[1][ct] = __builtin_amdgcn_mfma_f32_16x16x32_f16(kf, qf[1][kt], st[1][ct], 0, 0, 0);
            }
#pragma unroll
            for (int rt = 0; rt < 2; ++rt)
#pragma unroll
                for (int r = 0; r < 4; ++r)
                    st[rt][ct - 4][r] = __builtin_amdgcn_exp2f(st[rt][ct - 4][r]);
        }

        // ---- pack half0 + row-sum half0
        f16x8 pf[2][4];
#pragma unroll
        for (int rt = 0; rt < 2; ++rt)
#pragma unroll
            for (int kt2 = 0; kt2 < 2; ++kt2) {
                union { f16x8 v; unsigned u[4]; } pk;
#pragma unroll
                for (int t = 0; t < 2; ++t) {
                    pk.u[t * 2 + 0] = pkrtz(st[rt][kt2 * 2 + t][0], st[rt][kt2 * 2 + t][1]);
                    pk.u[t * 2 + 1] = pkrtz(st[rt][kt2 * 2 + t][2], st[rt][kt2 * 2 + t][3]);
                }
                pf[rt][kt2] = pk.v;
            }
#pragma unroll
        for (int kt2 = 0; kt2 < 2; ++kt2) {
            lacc[0] = __builtin_amdgcn_mfma_f32_16x16x32_f16(pf[0][kt2], vones, lacc[0], 0, 0, 0);
            lacc[1] = __builtin_amdgcn_mfma_f32_16x16x32_f16(pf[1][kt2], vones, lacc[1], 0, 0, 0);
        }

        // ---- PV half0 (kt2 0..1) interleaved with exp2(half1): MFMA || VALU
#pragma unroll
        for (int dt = 0; dt < 4; ++dt) {
#pragma unroll
            for (int kt2 = 0; kt2 < 2; ++kt2) {
                const f16x8 vf = *(const f16x8*)&vb[dt * 1024 + vbase[kt2]];
                o[0][dt] = __builtin_amdgcn_mfma_f32_16x16x32_f16(pf[0][kt2], vf, o[0][dt], 0, 0, 0);
                o[1][dt] = __builtin_amdgcn_mfma_f32_16x16x32_f16(pf[1][kt2], vf, o[1][dt], 0, 0, 0);
            }
#pragma unroll
            for (int rt = 0; rt < 2; ++rt)
#pragma unroll
                for (int r = 0; r < 4; ++r)
                    st[rt][4 + dt][r] = __builtin_amdgcn_exp2f(st[rt][4 + dt][r]);
        }

        // ---- pack half1 + row-sum half1
#pragma unroll
        for (int rt = 0; rt < 2; ++rt)
#pragma unroll
            for (int kt2 = 2; kt2 < 4; ++kt2) {
                union { f16x8 v; unsigned u[4]; } pk;
#pragma unroll
                for (int t = 0; t < 2; ++t) {
                    pk.u[t * 2 + 0] = pkrtz(st[rt][kt2 * 2 + t][0], st[rt][kt2 * 2 + t][1]);
                    pk.u[t * 2 + 1] = pkrtz(st[rt][kt2 * 2 + t][2], st[rt][kt2 * 2 + t][3]);
                }
                pf[rt][kt2] = pk.v;
            }
#pragma unroll
        for (int kt2 = 2; kt2 < 4; ++kt2) {
            lacc[0] = __builtin_amdgcn_mfma_f32_16x16x32_f16(pf[0][kt2], vones, lacc[0], 0, 0, 0);
            lacc[1] = __builtin_amdgcn_mfma_f32_16x16x32_f16(pf[1][kt2], vones, lacc[1], 0, 0, 0);
        }

        // ---- PV half1 (kt2 2..3): pure MFMA
        __builtin_amdgcn_s_setprio(1);
#pragma unroll
        for (int dt = 0; dt < 4; ++dt)
#pragma unroll
            for (int kt2 = 2; kt2 < 4; ++kt2) {
                const f16x8 vf = *(const f16x8*)&vb[dt * 1024 + vbase[kt2]];
                o[0][dt] = __builtin_amdgcn_mfma_f32_16x16x32_f16(pf[0][kt2], vf, o[0][dt], 0, 0, 0);
                o[1][dt] = __builtin_amdgcn_mfma_f32_16x16x32_f16(pf[1][kt2], vf, o[1][dt], 0, 0, 0);
            }
        __builtin_amdgcn_s_setprio(0);
    }

    const int b = bh >> 4;
    const int h = bh & 15;
#pragma unroll
    for (int rt = 0; rt < 2; ++rt)
#pragma unroll
    for (int r = 0; r < 4; ++r) {
        const float lr = 1.0f / lacc[rt][r];
        const int srow2 = q0 + w * 32 + rt * 16 + lq * 4 + r;
        const size_t base = ((size_t)b * SEQ + srow2) * DIMSZ + h * HDIM;
#pragma unroll
        for (int dt = 0; dt < 4; ++dt)
            CTXh[base + dt * 16 + lm] = f2h(o[rt][dt][r] * lr);
    }
}

// ---------------------------------------------------------------------------
// Output projection: fp16 (CTXh x Woh). (r10 form restored — two-barrier
// BK=64, XOR-8 layout; r11's single-barrier dbuf reverted.)
// ---------------------------------------------------------------------------
__global__ __launch_bounds__(256) void oproj_gemm(
    const ushort* __restrict__ Ah_g, const ushort* __restrict__ Bh_g,
    const float* __restrict__ bias, float* __restrict__ out)
{
    __shared__ __align__(16) ushort smem[12288];

    const int tid = threadIdx.x;
    const int wave = tid >> 6;
    const int lane = tid & 63;
    const int lm = lane & 15;
    const int lq = lane >> 4;
    const int wy = wave >> 1;
    const int wx = wave & 1;
    const int m0 = blockIdx.x * 64;
    const int n0 = blockIdx.y * 128;

    const int c = tid & 7;
    const int r0 = tid >> 3;               // 0..31
    const int g = c ^ (r0 & 7);
    const ushort* gah = Ah_g + (size_t)(m0 + r0) * DIMSZ + g * 8;
    const ushort* gbh = Bh_g + (size_t)(n0 + r0) * DIMSZ + g * 8;
    const int tofs = tid * 8;

    int aofs[2][2], bofs[4][2];
#pragma unroll
    for (int kt = 0; kt < 2; ++kt) {
        const int slot = ((kt * 4 + lq) ^ (lm & 7)) << 3;
#pragma unroll
        for (int i = 0; i < 2; ++i)
            aofs[i][kt] = (wy * 32 + i * 16 + lm) * 64 + slot;
#pragma unroll
        for (int j = 0; j < 4; ++j)
            bofs[j][kt] = 4096 + (wx * 64 + j * 16 + lm) * 64 + slot;
    }

    f32x4 acc[2][4] = {};

    {
        gld16(gah, smem + tofs);
        gld16(gah + 32 * DIMSZ, smem + 2048 + tofs);
#pragma unroll
        for (int gg = 0; gg < 4; ++gg)
            gld16(gbh + gg * 32 * DIMSZ, smem + 4096 + gg * 2048 + tofs);
    }

    for (int kk = 0; kk < 16; ++kk) {
        __syncthreads();   // staged

        f16x8 a0[2], b0[4];
#pragma unroll
        for (int i = 0; i < 2; ++i) a0[i] = *(const f16x8*)&smem[aofs[i][0]];
#pragma unroll
        for (int j = 0; j < 4; ++j) b0[j] = *(const f16x8*)&smem[bofs[j][0]];
#pragma unroll
        for (int i = 0; i < 2; ++i)
#pragma unroll
            for (int j = 0; j < 4; ++j)
                acc[i][j] = __builtin_amdgcn_mfma_f32_16x16x32_f16(a0[i], b0[j], acc[i][j], 0, 0, 0);

        f16x8 a1[2], b1[4];
#pragma unroll
        for (int i = 0; i < 2; ++i) a1[i] = *(const f16x8*)&smem[aofs[i][1]];
#pragma unroll
        for (int j = 0; j < 4; ++j) b1[j] = *(const f16x8*)&smem[bofs[j][1]];

        __syncthreads();   // reads drained

        if (kk + 1 < 16) {
            const int k0 = (kk + 1) * 64;
            gld16(gah + k0, smem + tofs);
            gld16(gah + 32 * DIMSZ + k0, smem + 2048 + tofs);
#pragma unroll
            for (int gg = 0; gg < 4; ++gg)
                gld16(gbh + gg * 32 * DIMSZ + k0, smem + 4096 + gg * 2048 + tofs);
        }

#pragma unroll
        for (int i = 0; i < 2; ++i)
#pragma unroll
            for (int j = 0; j < 4; ++j)
                acc[i][j] = __builtin_amdgcn_mfma_f32_16x16x32_f16(a1[i], b1[j], acc[i][j], 0, 0, 0);
    }

#pragma unroll
    for (int j = 0; j < 4; ++j) {
        const int nc = n0 + wx * 64 + j * 16 + lm;
        const float bb = bias[nc];
#pragma unroll
        for (int i = 0; i < 2; ++i) {
            const int mb = m0 + wy * 32 + i * 16 + lq * 4;
#pragma unroll
            for (int rr = 0; rr < 4; ++rr)
                out[(size_t)(mb + rr) * DIMSZ + nc] = acc[i][j][rr] + bb;
        }
    }
}

// ---------------------------------------------------------------------------
extern "C" void kernel_launch(void* const* d_in, const int* in_sizes, int n_in,
                              void* d_out, int out_size, void* d_ws, size_t ws_size,
                              hipStream_t stream)
{
    const float* x  = (const float*)d_in[0];
    const float* Wq = (const float*)d_in[1];
    const float* bq = (const float*)d_in[2];
    const float* Wk = (const float*)d_in[3];
    const float* bk = (const float*)d_in[4];
    const float* Wv = (const float*)d_in[5];
    const float* bv = (const float*)d_in[6];
    const float* Wo = (const float*)d_in[7];
    const float* bo = (const float*)d_in[8];
    float* out = (float*)d_out;

    const size_t elems = (size_t)NROWS * DIMSZ;   // 4M
    ushort* Qb   = (ushort*)d_ws;                 // 8MB
    ushort* Kb   = Qb + elems;                    // 8MB
    ushort* Vt   = Kb + elems;                    // 8MB
    ushort* CTXh = Vt + elems;                    // 8MB (overlay: Xh)
    ushort* Wh   = CTXh + elems;                  // 6MB
    ushort* Woh  = Wh + 3 * (1 << 20);            // 2MB  (peak 40MB)
    ushort* Xh   = CTXh;                          // dead before flash writes CTX

    convert_all<<<4096, 256, 0, stream>>>(x, Wq, Wk, Wv, Wo, Xh, Wh, Woh);

    qkv_gemm<<<dim3(32, 24), 256, 0, stream>>>(Xh, Wh, bq, bk, bv, Qb, Kb, Vt);

    flash_attn_mfma<<<dim3(SEQ / 128, BATCH * NHEAD), 256, 0, stream>>>(Qb, Kb, Vt, CTXh);

    oproj_gemm<<<dim3(64, 8), 256, 0, stream>>>(CTXh, Woh, bo, out);
}

// Round 13
// 168.770 us; speedup vs baseline: 1.0675x; 1.0139x over previous
//
#include <hip/hip_runtime.h>
#include <hip/hip_bf16.h>
#include <math.h>

#define DIMSZ 1024
#define NHEAD 16
#define HDIM 64
#define BATCH 2
#define SEQ 2048
#define NROWS (BATCH * SEQ)   // 4096

// softmax in exp2 domain: fold 1/sqrt(64) * log2(e) into Q at conversion
#define QSCALE 0.18033688011112042592f

typedef __attribute__((ext_vector_type(8))) _Float16 f16x8;
typedef __attribute__((ext_vector_type(2))) __fp16 fp16x2;   // cvt_pkrtz return type
typedef __attribute__((ext_vector_type(4))) float f32x4;

// float -> fp16 RNE, as bit pattern
__device__ __forceinline__ ushort f2h(float x) {
    union { _Float16 h; ushort u; } cv;
    cv.h = (_Float16)x;
    return cv.u;
}

// packed f32x2 -> f16x2 (RTZ), one v_cvt_pkrtz_f16_f32
__device__ __forceinline__ unsigned pkrtz(float a, float b) {
    union { fp16x2 v; unsigned u; } c;
    c.v = __builtin_amdgcn_cvt_pkrtz(a, b);
    return c.u;
}

__device__ __forceinline__ void gld16(const void* g, void* l) {
    __builtin_amdgcn_global_load_lds((const __attribute__((address_space(1))) void*)g,
                                     (__attribute__((address_space(3))) void*)l,
                                     16, 0, 0);
}

// ---------------------------------------------------------------------------
// Convert everything to fp16 single-plane. (unchanged)
// ---------------------------------------------------------------------------
__global__ __launch_bounds__(256) void convert_all(
    const float* __restrict__ x,
    const float* __restrict__ Wq, const float* __restrict__ Wk,
    const float* __restrict__ Wv, const float* __restrict__ Wo,
    ushort* __restrict__ Xh, ushort* __restrict__ Wh, ushort* __restrict__ Woh)
{
    const int b = blockIdx.x;
    const float* src;
    ushort* dst;
    size_t off;
    if (b < 2048)      { src = x;  dst = Xh;             off = (size_t)b * 2048; }
    else if (b < 2560) { src = Wq; dst = Wh;             off = (size_t)(b - 2048) * 2048; }
    else if (b < 3072) { src = Wk; dst = Wh + (1 << 20); off = (size_t)(b - 2560) * 2048; }
    else if (b < 3584) { src = Wv; dst = Wh + 2 * (1 << 20); off = (size_t)(b - 3072) * 2048; }
    else               { src = Wo; dst = Woh;            off = (size_t)(b - 3584) * 2048; }

    const size_t i = off + (size_t)threadIdx.x * 8;
    const float4 f0 = *(const float4*)&src[i];
    const float4 f1 = *(const float4*)&src[i + 4];
    uint4 hv;
    hv.x = (unsigned)f2h(f0.x) | ((unsigned)f2h(f0.y) << 16);
    hv.y = (unsigned)f2h(f0.z) | ((unsigned)f2h(f0.w) << 16);
    hv.z = (unsigned)f2h(f1.x) | ((unsigned)f2h(f1.y) << 16);
    hv.w = (unsigned)f2h(f1.z) | ((unsigned)f2h(f1.w) << 16);
    *(uint4*)&dst[i] = hv;
}

// ---------------------------------------------------------------------------
// Fused QKV GEMM, fp16. (r10 form — two-barrier BK=64 loop, XOR-8 layout)
// ---------------------------------------------------------------------------
__global__ __launch_bounds__(256, 3) void qkv_gemm(
    const ushort* __restrict__ Xh,
    const ushort* __restrict__ Wh,
    const float* __restrict__ bq, const float* __restrict__ bk,
    const float* __restrict__ bv,
    ushort* __restrict__ Qb, ushort* __restrict__ Kb, ushort* __restrict__ Vt)
{
    __shared__ __align__(16) ushort smem[17408];

    const int tid = threadIdx.x;
    const int wave = tid >> 6;
    const int lane = tid & 63;
    const int lm = lane & 15;
    const int lq = lane >> 4;
    const int wy = wave >> 1;
    const int wx = wave & 1;
    const int m0 = blockIdx.x * 128;
    const int nbase = blockIdx.y * 128;

    const int c = tid & 7;
    const int r0 = tid >> 3;               // 0..31
    const int g = c ^ (r0 & 7);
    const ushort* gah = Xh + (size_t)(m0 + r0) * DIMSZ + g * 8;
    const ushort* gbh = Wh + (size_t)(nbase + r0) * DIMSZ + g * 8;
    const int tofs = tid * 8;

    int aofs[4][2], bofs[4][2];
#pragma unroll
    for (int i = 0; i < 4; ++i)
#pragma unroll
        for (int kt = 0; kt < 2; ++kt) {
            const int slot = ((kt * 4 + lq) ^ (lm & 7)) << 3;
            aofs[i][kt] = (wy * 64 + i * 16 + lm) * 64 + slot;
            bofs[i][kt] = 8192 + (wx * 64 + i * 16 + lm) * 64 + slot;
        }

    f32x4 acc[4][4] = {};

    // stage k-tile 0 (8 gld16: 4 A row-groups + 4 B row-groups)
#pragma unroll
    for (int gg = 0; gg < 4; ++gg) {
        gld16(gah + gg * 32 * DIMSZ, smem + gg * 2048 + tofs);
        gld16(gbh + gg * 32 * DIMSZ, smem + 8192 + gg * 2048 + tofs);
    }

    for (int kk = 0; kk < 16; ++kk) {
        __syncthreads();   // barrier1: staging for tile kk landed (vmcnt drain)

        f16x8 a0[4], b0[4];
#pragma unroll
        for (int i = 0; i < 4; ++i) {
            a0[i] = *(const f16x8*)&smem[aofs[i][0]];
            b0[i] = *(const f16x8*)&smem[bofs[i][0]];
        }
#pragma unroll
        for (int i = 0; i < 4; ++i)
#pragma unroll
            for (int j = 0; j < 4; ++j)
                acc[i][j] = __builtin_amdgcn_mfma_f32_16x16x32_f16(a0[i], b0[j], acc[i][j], 0, 0, 0);

        f16x8 a1[4], b1[4];
#pragma unroll
        for (int i = 0; i < 4; ++i) {
            a1[i] = *(const f16x8*)&smem[aofs[i][1]];
            b1[i] = *(const f16x8*)&smem[bofs[i][1]];
        }

        __syncthreads();   // barrier2: all frag reads drained before overwrite

        if (kk + 1 < 16) {
            const int k0 = (kk + 1) * 64;
#pragma unroll
            for (int gg = 0; gg < 4; ++gg) {
                gld16(gah + gg * 32 * DIMSZ + k0, smem + gg * 2048 + tofs);
                gld16(gbh + gg * 32 * DIMSZ + k0, smem + 8192 + gg * 2048 + tofs);
            }
        }

#pragma unroll
        for (int i = 0; i < 4; ++i)
#pragma unroll
            for (int j = 0; j < 4; ++j)
                acc[i][j] = __builtin_amdgcn_mfma_f32_16x16x32_f16(a1[i], b1[j], acc[i][j], 0, 0, 0);
    }

    const int mat = blockIdx.y >> 3;      // 0:Q 1:K 2:V (block-uniform)
    const float* bias = (mat == 0) ? bq : (mat == 1) ? bk : bv;
    const int nloc0 = (blockIdx.y & 7) * 128;
    const int b = m0 >> 11;
    const int s0 = m0 & (SEQ - 1);
    ushort* sf = smem;

    __syncthreads();   // K-loop traffic complete before smem reuse

    if (mat == 2) {
        // ---- V: transpose to [d][s], key-permuted within 32-blocks
#pragma unroll
        for (int j = 0; j < 4; ++j) {
            const int nc = nloc0 + wx * 64 + j * 16 + lm;
            const float bb = bias[nc];
            const int d = j * 16 + lm;
#pragma unroll
            for (int i = 0; i < 4; ++i) {
                const int ss = wy * 64 + (i >> 1) * 32 + lq * 8 + (i & 1) * 4;
                ushort4 pk;
                pk.x = f2h(acc[i][j][0] + bb);
                pk.y = f2h(acc[i][j][1] + bb);
                pk.z = f2h(acc[i][j][2] + bb);
                pk.w = f2h(acc[i][j][3] + bb);
                *(ushort4*)&sf[(wx * 64 + d) * 136 + ss] = pk;
            }
        }
        __syncthreads();
#pragma unroll
        for (int p = 0; p < 8; ++p) {
            const int idx = p * 256 + tid;
            const int row = idx >> 4;
            const int hh = row >> 6;
            const int d = row & 63;
            const int sseg = (idx & 15) * 8;
            const uint4 v = *(const uint4*)&sf[row * 136 + sseg];
            const int hg = (nloc0 >> 6) + hh;
            *(uint4*)&Vt[((size_t)(b * NHEAD + hg) * HDIM + d) * SEQ + s0 + sseg] = v;
        }
    } else {
        // ---- Q/K: [s][d] tile in LDS, uint4 coalesced out
        ushort* dst = (mat == 0) ? Qb : Kb;
        const float sc = (mat == 0) ? QSCALE : 1.0f;
#pragma unroll
        for (int j = 0; j < 4; ++j) {
            const int col = wx * 64 + j * 16 + lm;
            const float bb = bias[nloc0 + col];
#pragma unroll
            for (int i = 0; i < 4; ++i) {
                const int rbase = wy * 64 + i * 16 + lq * 4;
#pragma unroll
                for (int rr = 0; rr < 4; ++rr)
                    sf[(rbase + rr) * 136 + col] = f2h((acc[i][j][rr] + bb) * sc);
            }
        }
        __syncthreads();
#pragma unroll
        for (int p = 0; p < 8; ++p) {
            const int idx = p * 256 + tid;
            const int row = idx >> 4;
            const int seg = idx & 15;
            const uint4 v = *(const uint4*)&sf[row * 136 + seg * 8];
            const int nc0 = nloc0 + seg * 8;
            const int h = nc0 >> 6;
            const int d = nc0 & 63;
            *(uint4*)&dst[((size_t)(b * NHEAD + h) * SEQ + s0 + row) * HDIM + d] = v;
        }
    }
}

// ---------------------------------------------------------------------------
// MFMA flash attention, S^T formulation, fp16.
// r13: XCD-CLUSTERED WORK MAP — remap linear block id L so XCD x (= L%8 by
//      round-robin dispatch) hosts exactly heads {x, x+8, x+16, x+24}:
//      per-XCD KV working set = 4 heads x 512KB = 2MB, fully L2-resident
//      (4MB/XCD). r12 FETCH=70MB of HBM re-reads on 16MB unique KV = every
//      XCD re-fetching all 32 heads. After this, K/V staging hits L2.
//      Phase stagger re-keyed to q0 bit3 (co-resident pairs L, L+256 now
//      share bh but differ in q0idx by 8). Compute body = r9 form (r12's
//      intra-wave reorder measured −2.3 µs; reverted).
// ---------------------------------------------------------------------------
__global__ __launch_bounds__(256, 2) void flash_attn_mfma(
    const ushort* __restrict__ Qb, const ushort* __restrict__ Kb,
    const ushort* __restrict__ Vt, ushort* __restrict__ CTXh)
{
    __shared__ __align__(16) ushort Ks[2][8192];   // 128 s-rows x 64 k (16KB each)
    __shared__ __align__(16) ushort Vs[2][8192];   // 2 halves x [64 d x 64 s] (16KB each)

    const int tid = threadIdx.x;
    const int w = tid >> 6;        // 0..3
    const int l = tid & 63;
    const int lm = l & 15;
    const int lq = l >> 4;
    const int NCH = SEQ / 128;     // 16

    // XCD-clustered remap: L%8 = XCD (round-robin dispatch); cluster 4 heads
    // per XCD; q0 runs over slot>>2.
    const int L = blockIdx.x + 16 * blockIdx.y;
    const int xcd = L & 7;
    const int slot = L >> 3;                 // 0..63
    const int bh = xcd + 8 * (slot & 3);     // heads {xcd, xcd+8, xcd+16, xcd+24}
    const int q0i = slot >> 2;               // 0..15
    const int q0 = q0i * 128;
    const int ch0 = q0i & 8;                 // co-resident pair offset (q0i differs by 8)

    const ushort* Kg = Kb + (size_t)bh * SEQ * HDIM;
    const ushort* Vg = Vt + (size_t)bh * HDIM * SEQ;

    const int sr8 = l >> 3;                          // 0..7
    const int sg_ = (l & 7) ^ (sr8 & 7);

    f16x8 qf[2][2];
#pragma unroll
    for (int rt = 0; rt < 2; ++rt)
#pragma unroll
        for (int kt = 0; kt < 2; ++kt)
            qf[rt][kt] = *(const f16x8*)&Qb[((size_t)bh * SEQ + q0 + w * 32 + rt * 16 + lm) * HDIM + kt * 32 + lq * 8];

    int kbase[2], vbase[4];
#pragma unroll
    for (int kt = 0; kt < 2; ++kt)
        kbase[kt] = lm * 64 + (((kt * 4 + lq) ^ (lm & 7)) << 3);
#pragma unroll
    for (int kt2 = 0; kt2 < 4; ++kt2)
        vbase[kt2] = (kt2 >> 1) * 4096 + lm * 64 + ((((kt2 & 1) * 4 + lq) ^ (lm & 7)) << 3);

    f16x8 vones;
#pragma unroll
    for (int i = 0; i < 8; ++i) vones[i] = (_Float16)1.0f;

    f32x4 o[2][4] = {};
    f32x4 lacc[2] = {};

    {
        const int kc0 = ch0 * 128;
#pragma unroll
        for (int p = 0; p < 2; ++p) {
            const int kr = kc0 + p * 64 + w * 16 + sr8;
            gld16(Kg + (size_t)kr * HDIM + sg_ * 8,        &Ks[0][0] + p * 4096 + w * 1024);
            gld16(Kg + (size_t)(kr + 8) * HDIM + sg_ * 8,  &Ks[0][0] + p * 4096 + w * 1024 + 512);
            const int vr = w * 16 + sr8;
            gld16(Vg + (size_t)vr * SEQ + kc0 + p * 64 + sg_ * 8,       &Vs[0][0] + p * 4096 + w * 1024);
            gld16(Vg + (size_t)(vr + 8) * SEQ + kc0 + p * 64 + sg_ * 8, &Vs[0][0] + p * 4096 + w * 1024 + 512);
        }
    }

    for (int it = 0; it < NCH; ++it) {
        __syncthreads();

        if (it + 1 < NCH) {
            const int kc = ((ch0 + it + 1) & (NCH - 1)) * 128;
            ushort* kb_n = &Ks[(it + 1) & 1][0];
            ushort* vb_n = &Vs[(it + 1) & 1][0];
#pragma unroll
            for (int p = 0; p < 2; ++p) {
                const int kr = kc + p * 64 + w * 16 + sr8;
                gld16(Kg + (size_t)kr * HDIM + sg_ * 8,        kb_n + p * 4096 + w * 1024);
                gld16(Kg + (size_t)(kr + 8) * HDIM + sg_ * 8,  kb_n + p * 4096 + w * 1024 + 512);
                const int vr = w * 16 + sr8;
                gld16(Vg + (size_t)vr * SEQ + kc + p * 64 + sg_ * 8,       vb_n + p * 4096 + w * 1024);
                gld16(Vg + (size_t)(vr + 8) * SEQ + kc + p * 64 + sg_ * 8, vb_n + p * 4096 + w * 1024 + 512);
            }
        }

        const ushort* kb = &Ks[it & 1][0];
        const ushort* vb = &Vs[it & 1][0];

        f32x4 st[2][8] = {};
        __builtin_amdgcn_s_setprio(1);
#pragma unroll
        for (int ct = 0; ct < 8; ++ct)
#pragma unroll
            for (int kt = 0; kt < 2; ++kt) {
                const f16x8 kf = *(const f16x8*)&kb[ct * 1024 + kbase[kt]];
                st[0][ct] = __builtin_amdgcn_mfma_f32_16x16x32_f16(kf, qf[0][kt], st[0][ct], 0, 0, 0);
                st[1][ct] = __builtin_amdgcn_mfma_f32_16x16x32_f16(kf, qf[1][kt], st[1][ct], 0, 0, 0);
            }
        __builtin_amdgcn_s_setprio(0);

#pragma unroll
        for (int rt = 0; rt < 2; ++rt)
#pragma unroll
            for (int ct = 0; ct < 8; ++ct)
#pragma unroll
                for (int r = 0; r < 4; ++r)
                    st[rt][ct][r] = __builtin_amdgcn_exp2f(st[rt][ct][r]);

        f16x8 pf[2][4];
#pragma unroll
        for (int rt = 0; rt < 2; ++rt)
#pragma unroll
            for (int kt2 = 0; kt2 < 4; ++kt2) {
                union { f16x8 v; unsigned u[4]; } pk;
#pragma unroll
                for (int t = 0; t < 2; ++t) {
                    pk.u[t * 2 + 0] = pkrtz(st[rt][kt2 * 2 + t][0], st[rt][kt2 * 2 + t][1]);
                    pk.u[t * 2 + 1] = pkrtz(st[rt][kt2 * 2 + t][2], st[rt][kt2 * 2 + t][3]);
                }
                pf[rt][kt2] = pk.v;
            }

        __builtin_amdgcn_s_setprio(1);
#pragma unroll
        for (int kt2 = 0; kt2 < 4; ++kt2) {
            lacc[0] = __builtin_amdgcn_mfma_f32_16x16x32_f16(pf[0][kt2], vones, lacc[0], 0, 0, 0);
            lacc[1] = __builtin_amdgcn_mfma_f32_16x16x32_f16(pf[1][kt2], vones, lacc[1], 0, 0, 0);
        }

#pragma unroll
        for (int dt = 0; dt < 4; ++dt)
#pragma unroll
            for (int kt2 = 0; kt2 < 4; ++kt2) {
                const f16x8 vf = *(const f16x8*)&vb[dt * 1024 + vbase[kt2]];
                o[0][dt] = __builtin_amdgcn_mfma_f32_16x16x32_f16(pf[0][kt2], vf, o[0][dt], 0, 0, 0);
                o[1][dt] = __builtin_amdgcn_mfma_f32_16x16x32_f16(pf[1][kt2], vf, o[1][dt], 0, 0, 0);
            }
        __builtin_amdgcn_s_setprio(0);
    }

    const int b = bh >> 4;
    const int h = bh & 15;
#pragma unroll
    for (int rt = 0; rt < 2; ++rt)
#pragma unroll
    for (int r = 0; r < 4; ++r) {
        const float lr = 1.0f / lacc[rt][r];
        const int srow2 = q0 + w * 32 + rt * 16 + lq * 4 + r;
        const size_t base = ((size_t)b * SEQ + srow2) * DIMSZ + h * HDIM;
#pragma unroll
        for (int dt = 0; dt < 4; ++dt)
            CTXh[base + dt * 16 + lm] = f2h(o[rt][dt][r] * lr);
    }
}

// ---------------------------------------------------------------------------
// Output projection: fp16 (CTXh x Woh). (r10 form — two-barrier BK=64,
// XOR-8 layout)
// ---------------------------------------------------------------------------
__global__ __launch_bounds__(256) void oproj_gemm(
    const ushort* __restrict__ Ah_g, const ushort* __restrict__ Bh_g,
    const float* __restrict__ bias, float* __restrict__ out)
{
    __shared__ __align__(16) ushort smem[12288];

    const int tid = threadIdx.x;
    const int wave = tid >> 6;
    const int lane = tid & 63;
    const int lm = lane & 15;
    const int lq = lane >> 4;
    const int wy = wave >> 1;
    const int wx = wave & 1;
    const int m0 = blockIdx.x * 64;
    const int n0 = blockIdx.y * 128;

    const int c = tid & 7;
    const int r0 = tid >> 3;               // 0..31
    const int g = c ^ (r0 & 7);
    const ushort* gah = Ah_g + (size_t)(m0 + r0) * DIMSZ + g * 8;
    const ushort* gbh = Bh_g + (size_t)(n0 + r0) * DIMSZ + g * 8;
    const int tofs = tid * 8;

    int aofs[2][2], bofs[4][2];
#pragma unroll
    for (int kt = 0; kt < 2; ++kt) {
        const int slot = ((kt * 4 + lq) ^ (lm & 7)) << 3;
#pragma unroll
        for (int i = 0; i < 2; ++i)
            aofs[i][kt] = (wy * 32 + i * 16 + lm) * 64 + slot;
#pragma unroll
        for (int j = 0; j < 4; ++j)
            bofs[j][kt] = 4096 + (wx * 64 + j * 16 + lm) * 64 + slot;
    }

    f32x4 acc[2][4] = {};

    {
        gld16(gah, smem + tofs);
        gld16(gah + 32 * DIMSZ, smem + 2048 + tofs);
#pragma unroll
        for (int gg = 0; gg < 4; ++gg)
            gld16(gbh + gg * 32 * DIMSZ, smem + 4096 + gg * 2048 + tofs);
    }

    for (int kk = 0; kk < 16; ++kk) {
        __syncthreads();   // staged

        f16x8 a0[2], b0[4];
#pragma unroll
        for (int i = 0; i < 2; ++i) a0[i] = *(const f16x8*)&smem[aofs[i][0]];
#pragma unroll
        for (int j = 0; j < 4; ++j) b0[j] = *(const f16x8*)&smem[bofs[j][0]];
#pragma unroll
        for (int i = 0; i < 2; ++i)
#pragma unroll
            for (int j = 0; j < 4; ++j)
                acc[i][j] = __builtin_amdgcn_mfma_f32_16x16x32_f16(a0[i], b0[j], acc[i][j], 0, 0, 0);

        f16x8 a1[2], b1[4];
#pragma unroll
        for (int i = 0; i < 2; ++i) a1[i] = *(const f16x8*)&smem[aofs[i][1]];
#pragma unroll
        for (int j = 0; j < 4; ++j) b1[j] = *(const f16x8*)&smem[bofs[j][1]];

        __syncthreads();   // reads drained

        if (kk + 1 < 16) {
            const int k0 = (kk + 1) * 64;
            gld16(gah + k0, smem + tofs);
            gld16(gah + 32 * DIMSZ + k0, smem + 2048 + tofs);
#pragma unroll
            for (int gg = 0; gg < 4; ++gg)
                gld16(gbh + gg * 32 * DIMSZ + k0, smem + 4096 + gg * 2048 + tofs);
        }

#pragma unroll
        for (int i = 0; i < 2; ++i)
#pragma unroll
            for (int j = 0; j < 4; ++j)
                acc[i][j] = __builtin_amdgcn_mfma_f32_16x16x32_f16(a1[i], b1[j], acc[i][j], 0, 0, 0);
    }

#pragma unroll
    for (int j = 0; j < 4; ++j) {
        const int nc = n0 + wx * 64 + j * 16 + lm;
        const float bb = bias[nc];
#pragma unroll
        for (int i = 0; i < 2; ++i) {
            const int mb = m0 + wy * 32 + i * 16 + lq * 4;
#pragma unroll
            for (int rr = 0; rr < 4; ++rr)
                out[(size_t)(mb + rr) * DIMSZ + nc] = acc[i][j][rr] + bb;
        }
    }
}

// ---------------------------------------------------------------------------
extern "C" void kernel_launch(void* const* d_in, const int* in_sizes, int n_in,
                              void* d_out, int out_size, void* d_ws, size_t ws_size,
                              hipStream_t stream)
{
    const float* x  = (const float*)d_in[0];
    const float* Wq = (const float*)d_in[1];
    const float* bq = (const float*)d_in[2];
    const float* Wk = (const float*)d_in[3];
    const float* bk = (const float*)d_in[4];
    const float* Wv = (const float*)d_in[5];
    const float* bv = (const float*)d_in[6];
    const float* Wo = (const float*)d_in[7];
    const float* bo = (const float*)d_in[8];
    float* out = (float*)d_out;

    const size_t elems = (size_t)NROWS * DIMSZ;   // 4M
    ushort* Qb   = (ushort*)d_ws;                 // 8MB
    ushort* Kb   = Qb + elems;                    // 8MB
    ushort* Vt   = Kb + elems;                    // 8MB
    ushort* CTXh = Vt + elems;                    // 8MB (overlay: Xh)
    ushort* Wh   = CTXh + elems;                  // 6MB
    ushort* Woh  = Wh + 3 * (1 << 20);            // 2MB  (peak 40MB)
    ushort* Xh   = CTXh;                          // dead before flash writes CTX

    convert_all<<<4096, 256, 0, stream>>>(x, Wq, Wk, Wv, Wo, Xh, Wh, Woh);

    qkv_gemm<<<dim3(32, 24), 256, 0, stream>>>(Xh, Wh, bq, bk, bv, Qb, Kb, Vt);

    flash_attn_mfma<<<dim3(SEQ / 128, BATCH * NHEAD), 256, 0, stream>>>(Qb, Kb, Vt, CTXh);

    oproj_gemm<<<dim3(64, 8), 256, 0, stream>>>(CTXh, Woh, bo, out);
}